// Round 4
// baseline (245.433 us; speedup 1.0000x reference)
//
#include <hip/hip_runtime.h>

// x: (8, 64, 256, 256) fp32; alpha: (1,64,1,1) fp32
// out = x + alpha[c] * sum_{3x3 zero-padded} |x - neighbor|
//
// One wave (64 lanes x float4) = one full 256-wide row.
// Each wave: 8 output rows from 10 loaded rows (register halo reuse, 1.25x amp).
// Phase 1: 10 independent global float4 loads (160B MLP/thread).
// Phase 2: shuffles for left/right halo (lane 0/63 -> 0 == zero pad).
// Phase 3: compute (self-term skipped) + nontemporal float4 stores.
// Block = 4 waves = 32-row slab. Grid = 512 images * 8 slabs = 4096 blocks,
// XCD-swizzled so contiguous slabs share an XCD L2.

constexpr int H = 256;
constexpr int W = 256;
constexpr int C = 64;

typedef float vfloat4 __attribute__((ext_vector_type(4)));  // native vec for nontemporal

__global__ __launch_bounds__(256) void adc_kernel(
    const float* __restrict__ x,
    const float* __restrict__ alpha,
    float* __restrict__ out)
{
    const int lane = threadIdx.x & 63;
    const int wave = threadIdx.x >> 6;            // 0..3

    // XCD swizzle: dispatch round-robins blocks over 8 XCDs; remap so each
    // XCD gets a contiguous range of work (images/slabs) for L2 halo reuse.
    const int b    = blockIdx.x;                  // 0..4095
    const int work = (b & 7) * 512 + (b >> 3);
    const long img = work >> 3;                   // 0..511 (b*C + c)
    const int  s8  = work & 7;
    const int  y0  = s8 * 32 + wave * 8;          // first output row of this wave
    const int  c   = (int)(img & (C - 1));

    const float  a    = alpha[c];
    const float* imgp = x   + img * (long)(H * W);
    float*       outp = out + img * (long)(H * W);
    const int    w0   = lane * 4;

    // Phase 1: load 10 rows (y0-1 .. y0+8), zero-padded rows -> 0.
    float4 cr[10];
#pragma unroll
    for (int r = 0; r < 10; ++r) {
        const int yy = y0 + r - 1;
        cr[r] = make_float4(0.f, 0.f, 0.f, 0.f);
        if (yy >= 0 && yy < H)
            cr[r] = *(const float4*)(imgp + (long)yy * W + w0);
    }

    // Phase 2: build 10x6 windows with shuffled halos.
    float v[10][6];
#pragma unroll
    for (int r = 0; r < 10; ++r) {
        v[r][1] = cr[r].x; v[r][2] = cr[r].y; v[r][3] = cr[r].z; v[r][4] = cr[r].w;
        const float left  = __shfl_up(cr[r].w, 1);
        const float right = __shfl_down(cr[r].x, 1);
        v[r][0] = (lane == 0)  ? 0.f : left;    // w==0 edge -> zero pad
        v[r][5] = (lane == 63) ? 0.f : right;   // w==W edge -> zero pad
    }

    // Phase 3: 8 output rows x 4 cols. Self term |x-x|==0 skipped.
#pragma unroll
    for (int o = 0; o < 8; ++o) {
        vfloat4 res;
#pragma unroll
        for (int j = 0; j < 4; ++j) {
            const float xc = v[o + 1][j + 1];
            float s = 0.f;
#pragma unroll
            for (int r = 0; r < 3; ++r)
#pragma unroll
                for (int d = 0; d < 3; ++d)
                    if (!(r == 1 && d == 1))
                        s += fabsf(xc - v[o + r][j + d]);
            res[j] = fmaf(a, s, xc);
        }
        __builtin_nontemporal_store(res, (vfloat4*)(outp + (long)(y0 + o) * W + w0));
    }
}

extern "C" void kernel_launch(void* const* d_in, const int* in_sizes, int n_in,
                              void* d_out, int out_size, void* d_ws, size_t ws_size,
                              hipStream_t stream)
{
    const float* x     = (const float*)d_in[0];
    const float* alpha = (const float*)d_in[1];
    float*       out   = (float*)d_out;

    const int grid = 8 * C * (H / 32);   // 512 images * 8 slabs = 4096
    adc_kernel<<<grid, 256, 0, stream>>>(x, alpha, out);
}